// Round 8
// baseline (110.134 us; speedup 1.0000x reference)
//
#include <hip/hip_runtime.h>
#include <math.h>

#define NH 64
#define NG 32
#define YROW 68   // ytile [h][t] row stride (dwords): 16B-aligned rows for b128 writes (R7: 0 conflicts)

// wave-uniform lane broadcast -> v_readlane (SGPR result; no LDS bus traffic)
__device__ __forceinline__ float bcast(float v, int l) {
    return __int_as_float(__builtin_amdgcn_readlane(__float_as_int(v), l));
}

// 2 waves per block, one catchment per block (2048 waves = 2/SIMD, 4 blocks/CU).
// R8: all per-step broadcasts moved from the LDS data bus (1 KB delivery each) into
// the register file (v_readlane). LDS now carries only the ytile handoff.
// Wave 0 (crit): phase A in registers (lane j = step j's forcing), then per batch of
//   8 steps: 32 readlanes -> SGPRs + 8 pure-VALU steps + 2 b128 y-writes.
// Wave 1 (helper): phase C reduction of chunk c-1 (gq[h] via readlane of its own reg,
//   64 conflict-free b32 ytile reads, 64 fma) + out store.
// One __syncthreads per chunk; ytile double-buffered.
__global__ __launch_bounds__(128) void waternet_kernel(
    const float* __restrict__ x,   // [nt, ns, 4] fp32: P,E,T1,T2
    const float* __restrict__ xc,  // [ns, NG]
    const float* __restrict__ W3,  // [4*NH, NG]
    const float* __restrict__ b3,  // [4*NH]
    float* __restrict__ out,       // [nt, ns]
    int nt, int ns)
{
    // XCD-contiguous catchment map (verified R3: FETCH 64->8.3 MB, WRITE 32->4 MB)
    const int b    = blockIdx.x;
    const int s    = (b & 7) * (ns >> 3) + (b >> 3);
    const int tid  = threadIdx.x;
    const int lane = tid & 63;
    const bool crit = (tid < 64);

    __shared__ float ytile[2][NH * YROW];  // [h][t] Hn tile, double-buffered

    // ---- static gates (both waves; each keeps what it needs in registers) ----
    float wq[4];
    #pragma unroll
    for (int q = 0; q < 4; ++q) {
        const float4* row = reinterpret_cast<const float4*>(W3 + (size_t)(q * NH + lane) * NG);
        const float4* xr  = reinterpret_cast<const float4*>(xc + (size_t)s * NG);
        float a = 0.f;
        #pragma unroll
        for (int g = 0; g < NG / 4; ++g) {
            const float4 w  = row[g];
            const float4 xv = xr[g];
            a = fmaf(w.x, xv.x, a); a = fmaf(w.y, xv.y, a);
            a = fmaf(w.z, xv.z, a); a = fmaf(w.w, xv.w, a);
        }
        wq[q] = a + b3[q * NH + lane];
    }
    const float gm = expf(wq[0]) + 1.0f;               // melt gate (>0)
    const float ge = 1.0f / (1.0f + expf(-wq[1]));     // ET gate
    const float go = 1.0f / (1.0f + expf(-wq[2]));     // outflow gate
    float mx = wq[3];
    #pragma unroll
    for (int o = 32; o; o >>= 1) mx = fmaxf(mx, __shfl_xor(mx, o, 64));
    const float ex = expf(wq[3] - mx);
    float smx = ex;
    #pragma unroll
    for (int o = 32; o; o >>= 1) smx += __shfl_xor(smx, o, 64);
    const float ga = ex / smx;                         // softmax over h
    const float gq = go * ga;                          // helper's reduction weight
    const float gk = 1.0f - go;                        // H carryover factor

    const int nchunk = (nt + NH - 1) / NH;

    // phase A (in registers): forcing f -> Tr,Ps,Pl,E for this lane's step
    #define PHASE_A_REG(f) { \
        const float P = (f).x; Ev = (f).y; \
        const float T1 = (f).z, T2 = (f).w; \
        const float Ta  = 0.5f * (T1 + T2); \
        const float arg = fminf(1.f, fmaxf(-1.f, (T1 + T2) / (T2 - T1))); \
        const float aa  = fabsf(arg); \
        float p = fmaf(aa, -0.0012624911f, 0.0066700901f); \
        p = fmaf(aa, p, -0.0170881256f); p = fmaf(aa, p, 0.0308918810f); \
        p = fmaf(aa, p, -0.0501743046f); p = fmaf(aa, p, 0.0889789874f); \
        p = fmaf(aa, p, -0.2145988016f); p = fmaf(aa, p, 1.5707963050f); \
        const float rr0 = sqrtf(1.f - aa) * p;                  /* acos(|arg|) */ \
        const float ac  = (arg >= 0.f) ? rr0 : (3.14159265358979f - rr0); \
        const float rr  = 1.f - ac * (1.0f / 3.1415f);          /* module's PI */ \
        const float rP  = (T1 >= 0.f) ? 1.f : ((T2 <= 0.f) ? 0.f : rr); \
        Tr = fmaxf(Ta, 0.f); Ps = (1.f - rP) * P; Pl = rP * P; \
    }

    // one step from SGPR-broadcast scalars (each VALU op uses <=1 SGPR operand)
    #define STEP(sT, sP, sL, sE) { \
        const float M  = (sT) * gm; \
        const float Sm = fminf(S, M); \
        S = (S - Sm) + (sP); \
        const float qv = fmaf(-(sE), ge, Sm); \
        Hc = fmaxf(fmaf(gk, Hc, qv + (sL)), 0.f); \
    }

    if (crit) {
        float S = 0.f, Hc = 0.f;
        float Tr, Ps, Pl, Ev;

        int tp = min(lane, nt - 1);
        float4 f = *reinterpret_cast<const float4*>(x + ((size_t)tp * ns + s) * 4);

        #pragma unroll 1
        for (int c = 0; c < nchunk; ++c) {
            const int cnt = min(NH, nt - c * NH);
            PHASE_A_REG(f)

            // prefetch next chunk's forcing (vmcnt wait ~2000 cyc away -> hidden)
            tp = min((c + 1) * NH + lane, nt - 1);
            const float4 fn = *reinterpret_cast<const float4*>(x + ((size_t)tp * ns + s) * 4);

            float* yb = &ytile[c & 1][lane * YROW];

            if (cnt == NH) {
                #pragma unroll
                for (int bb = 0; bb < 8; ++bb) {
                    float sT[8], sP[8], sL[8], sE[8];
                    #pragma unroll
                    for (int k = 0; k < 8; ++k) {
                        sT[k] = bcast(Tr, bb * 8 + k);
                        sP[k] = bcast(Ps, bb * 8 + k);
                        sL[k] = bcast(Pl, bb * 8 + k);
                        sE[k] = bcast(Ev, bb * 8 + k);
                    }
                    float yv[8];
                    #pragma unroll
                    for (int k = 0; k < 8; ++k) { STEP(sT[k], sP[k], sL[k], sE[k]) yv[k] = Hc; }
                    *reinterpret_cast<float4*>(yb + bb * 8)     = make_float4(yv[0], yv[1], yv[2], yv[3]);
                    *reinterpret_cast<float4*>(yb + bb * 8 + 4) = make_float4(yv[4], yv[5], yv[6], yv[7]);
                }
            } else {                       // tail chunk (40 steps for nt=1000)
                const int nb = cnt / 8;
                for (int bb = 0; bb < nb; ++bb) {
                    float sT[8], sP[8], sL[8], sE[8];
                    #pragma unroll
                    for (int k = 0; k < 8; ++k) {
                        sT[k] = bcast(Tr, bb * 8 + k);
                        sP[k] = bcast(Ps, bb * 8 + k);
                        sL[k] = bcast(Pl, bb * 8 + k);
                        sE[k] = bcast(Ev, bb * 8 + k);
                    }
                    float yv[8];
                    #pragma unroll
                    for (int k = 0; k < 8; ++k) { STEP(sT[k], sP[k], sL[k], sE[k]) yv[k] = Hc; }
                    *reinterpret_cast<float4*>(yb + bb * 8)     = make_float4(yv[0], yv[1], yv[2], yv[3]);
                    *reinterpret_cast<float4*>(yb + bb * 8 + 4) = make_float4(yv[4], yv[5], yv[6], yv[7]);
                }
                for (int j = nb * 8; j < cnt; ++j) {           // remainder (0 for nt=1000)
                    const float sT = bcast(Tr, j), sP = bcast(Ps, j);
                    const float sL = bcast(Pl, j), sE = bcast(Ev, j);
                    STEP(sT, sP, sL, sE)
                    yb[j] = Hc;
                }
            }
            f = fn;
            __syncthreads();
        }
    } else {
        #pragma unroll 1
        for (int c = 0; c < nchunk; ++c) {
            if (c >= 1) {   // phase C: reduce chunk c-1 (always full); lane = t
                const float* yr = ytile[(c - 1) & 1];
                float z0 = 0.f, z1 = 0.f, z2 = 0.f, z3 = 0.f;
                #pragma unroll
                for (int h = 0; h < NH; h += 4) {
                    z0 = fmaf(bcast(gq, h + 0), yr[(h + 0) * YROW + lane], z0);
                    z1 = fmaf(bcast(gq, h + 1), yr[(h + 1) * YROW + lane], z1);
                    z2 = fmaf(bcast(gq, h + 2), yr[(h + 2) * YROW + lane], z2);
                    z3 = fmaf(bcast(gq, h + 3), yr[(h + 3) * YROW + lane], z3);
                }
                out[(size_t)((c - 1) * NH + lane) * ns + s] = (z0 + z1) + (z2 + z3);
            }
            __syncthreads();
        }
    }

    // epilogue: helper reduces the final chunk
    if (!crit) {
        const int c   = nchunk - 1;
        const int cnt = nt - c * NH;
        const float* yr = ytile[c & 1];
        float z0 = 0.f, z1 = 0.f, z2 = 0.f, z3 = 0.f;
        #pragma unroll
        for (int h = 0; h < NH; h += 4) {
            z0 = fmaf(bcast(gq, h + 0), yr[(h + 0) * YROW + lane], z0);
            z1 = fmaf(bcast(gq, h + 1), yr[(h + 1) * YROW + lane], z1);
            z2 = fmaf(bcast(gq, h + 2), yr[(h + 2) * YROW + lane], z2);
            z3 = fmaf(bcast(gq, h + 3), yr[(h + 3) * YROW + lane], z3);
        }
        if (lane < cnt)
            out[(size_t)(c * NH + lane) * ns + s] = (z0 + z1) + (z2 + z3);
    }
    #undef PHASE_A_REG
    #undef STEP
}

extern "C" void kernel_launch(void* const* d_in, const int* in_sizes, int n_in,
                              void* d_out, int out_size, void* d_ws, size_t ws_size,
                              hipStream_t stream) {
    const float* x  = (const float*)d_in[0];
    const float* xc = (const float*)d_in[1];
    const float* W3 = (const float*)d_in[2];
    const float* b3 = (const float*)d_in[3];
    float* out = (float*)d_out;

    const int nh = in_sizes[3] / 4;            // 64
    const int ng = in_sizes[2] / (4 * nh);     // 32
    const int ns = in_sizes[1] / ng;           // 1024
    const int nt = in_sizes[0] / (ns * 4);     // 1000

    waternet_kernel<<<dim3(ns), dim3(128), 0, stream>>>(x, xc, W3, b3, out, nt, ns);
}